// Round 7
// baseline (599.439 us; speedup 1.0000x reference)
//
#include <hip/hip_runtime.h>
#include <stdint.h>

#define N_NODES    50000
#define K_MAX      10
#define BATCH      64
#define T_STEPS    32
#define N_INPUTS   16
#define INPUT_BITS 64

// primary config: 2 WGs/CU on 256 CUs
#define NPW1   98                 // nodes per workgroup
#define NWG1   512                // 512 x 98 = 50176 >= 50000
#define NTHR1  448                // 4 threads (batch quarters) per node, 7 waves
// fallback config (round-4-proven shape) if coop launch is rejected
#define NPW2   224
#define NWG2   224
#define NTHR2  896

#define NPW_MAX 224
#define NBUF  (T_STEPS + 1)       // state ring: step t reads buf[t], writes buf[t+1]

#define BUF_STRIDE_B 400128u      // bytes per state buffer (50001*8 -> 128B aligned)

// ---------------- workspace layout (bytes) ----------------
#define OFF_BUFS   0u
#define OFF_XMASK  13204224u      // uint64[32*64]
#define OFF_CTR    13220608u      // 32 barrier counters, each on own 128B line
#define OFF_PLUT   13224704u      // uint8[50176*128] packed LUT (+pad)
// total ~19.66 MB

// ---------------- prep: init ring head, xor masks, sentinels, barrier ctrs ----------------
__global__ void prep_kernel(const int* __restrict__ x,
                            const int* __restrict__ init_states,
                            const int* __restrict__ input_nodes,
                            uint64_t* __restrict__ bufs,
                            uint64_t* __restrict__ xmask,
                            uint32_t* __restrict__ ctr) {
    const int gid = blockIdx.x * blockDim.x + threadIdx.x;
    const size_t strw = BUF_STRIDE_B / 8;
    if (gid < N_NODES) {
        int n = gid;
        // last occurrence of n in input_nodes (last-write-wins scatter semantics)
        int jm = -1;
        for (int j = 0; j < INPUT_BITS; ++j)
            if (input_nodes[j] == n) jm = j;
        uint64_t v = init_states[n] ? ~0ull : 0ull;   // same init for all 64 batches
        if (jm >= 0) {
            uint64_t m = 0ull;
            for (int b = 0; b < BATCH; ++b)
                m |= (uint64_t)(x[b * (T_STEPS * INPUT_BITS) + jm] & 1) << b;  // t = 0
            v ^= m;
        }
        bufs[n] = v;                                  // buf[0]
    } else if (gid < N_NODES + NBUF) {
        // zero sentinel word in every ring buffer (masked-off edges point here)
        bufs[(size_t)(gid - N_NODES) * strw + N_NODES] = 0ull;
    } else if (gid < N_NODES + NBUF + T_STEPS * INPUT_BITS) {
        int k = gid - (N_NODES + NBUF);
        int t = k >> 6, j = k & 63;
        uint64_t m = 0ull;
        for (int b = 0; b < BATCH; ++b)
            m |= (uint64_t)(x[b * (T_STEPS * INPUT_BITS) + t * INPUT_BITS + j] & 1) << b;
        xmask[k] = m;
    } else {
        int c = gid - (N_NODES + NBUF + T_STEPS * INPUT_BITS);
        if (c < T_STEPS) ctr[c * 32] = 0;             // replay-safe, 128B-line spaced
    }
}

// ---------------- pack LUT to bits (full-GPU, HBM-bound): 204.8 MB -> 6.4 MB ----------------
__global__ void lutpack_kernel(const int* __restrict__ lut,
                               uint64_t* __restrict__ plut) {
    const int tid = threadIdx.x;
    const int blk = blockIdx.x;                  // node
    const int lane = tid & 63, wave = tid >> 6;  // 16 waves x 64 lanes = 1024 entries
    int v = lut[(size_t)blk * 1024 + tid];
    uint64_t m = __ballot(v & 1);
    if (lane == 0) plut[(size_t)blk * 16 + wave] = m;
}

// ---------------- cooperative kernel: all 32 steps ----------------
// runtime (npw, nwg) so the same kernel serves primary and fallback configs
__global__ __launch_bounds__(NTHR2)
void reservoir_coop(const uint64_t* __restrict__ plut,
                    const int* __restrict__ adj,
                    const int* __restrict__ adjmask,
                    const int* __restrict__ input_nodes,
                    const uint64_t* __restrict__ xmask,
                    uint64_t* __restrict__ bufs,
                    uint32_t* __restrict__ ctr,
                    int npw, int nwg) {
    __shared__ uint8_t lutb[NPW_MAX * 128];   // bit-packed LUT rows for this WG

    const int tid = threadIdx.x;
    const int wg  = blockIdx.x;
    const int nbytes = npw * 128;

    // ---- stage packed LUT slice -> LDS (coalesced dwordx4) ----
    {
        const uint8_t* s = (const uint8_t*)plut + (size_t)wg * nbytes;
        for (int b = tid * 16; b < nbytes; b += blockDim.x * 16)
            *(uint4*)(lutb + b) = *(const uint4*)(s + b);
    }

    // ---- persistent per-thread setup (registers for all 32 steps) ----
    const int nl   = tid >> 2;            // local node
    const int q    = tid & 3;             // batch quarter (16 batches)
    const int node = wg * npw + nl;
    const bool valid = (nl < npw) && (node < N_NODES);
    const uint32_t qsh = (uint32_t)(q & 1) * 16;

    uint32_t off[K_MAX];                  // byte offsets of gather dwords (buffer-relative)
    uint32_t soff = 0;                    // store dword byte offset (even-q lanes)
    int jm = -1;
    if (valid) {
        #pragma unroll
        for (int k = 0; k < K_MAX; ++k) {
            int a  = adj[node * K_MAX + k];
            int mk = adjmask[node * K_MAX + k];
            // masked-off neighbor -> sentinel word N_NODES (always 0)
            off[k] = (uint32_t)(mk ? a : N_NODES) * 8u + (uint32_t)(q >> 1) * 4u;
        }
        for (int j = 0; j < INPUT_BITS; ++j)
            if (input_nodes[j] == node) jm = j;   // last occurrence
        soff = (uint32_t)node * 8u + (uint32_t)(q >> 1) * 4u;
    }
    const uint32_t* lut32 = (const uint32_t*)lutb;
    const uint32_t* xm32  = (const uint32_t*)xmask;
    const int rowbase = nl * 32;          // dword index of this node's LDS LUT row
    __syncthreads();                      // LDS staging complete

    for (int t = 0; t < T_STEPS; ++t) {
        // step t: read buf[t] (plain cached loads; ring guarantees freshness),
        //         write buf[t+1] (agent-scope, visible at L3).
        const char* src = (const char*)bufs + (size_t)t * BUF_STRIDE_B;
        char*       dst = (char*)bufs + (size_t)(t + 1) * BUF_STRIDE_B;
        if (valid) {
            uint32_t w[K_MAX];
            #pragma unroll
            for (int k = 0; k < K_MAX; ++k)
                w[k] = *(const uint32_t*)(src + off[k]) >> qsh;

            uint32_t o16 = 0;
            #pragma unroll
            for (int b = 0; b < 16; ++b) {
                uint32_t idx = 0;
                #pragma unroll
                for (int k = 0; k < K_MAX; ++k)
                    idx = (idx << 1) | ((w[k] >> b) & 1u);   // k=0 -> MSB (pow2 order)
                uint32_t d = lut32[rowbase + (idx >> 5)];
                o16 |= ((d >> (idx & 31)) & 1u) << b;
            }

            // pair lanes (q even/odd) combine to one dword store
            uint32_t hi = __shfl_down(o16, 1);
            if ((q & 1) == 0) {
                uint32_t o32 = o16 | (hi << 16);
                // fold next step's input-bit XOR into this write
                if (jm >= 0 && t < T_STEPS - 1)
                    o32 ^= xm32[((t + 1) * INPUT_BITS + jm) * 2 + (q >> 1)];
                __hip_atomic_store((uint32_t*)(dst + soff), o32,
                                   __ATOMIC_RELAXED, __HIP_MEMORY_SCOPE_AGENT);
            }
        }

        if (t < T_STEPS - 1) {
            // ---- global barrier: syncthreads drains vmcnt (stores at L3),
            //      then 1 agent atomic + poll per WG (proven r3/r4/r6). ----
            __syncthreads();
            if (tid == 0) {
                uint32_t* c = ctr + (size_t)t * 32;
                __hip_atomic_fetch_add(c, 1u, __ATOMIC_RELAXED, __HIP_MEMORY_SCOPE_AGENT);
                while (__hip_atomic_load(c, __ATOMIC_RELAXED, __HIP_MEMORY_SCOPE_AGENT)
                       < (uint32_t)nwg)
                    __builtin_amdgcn_s_sleep(2);
            }
            __syncthreads();
        }
    }
}

// ---------------- output: out[b,i] = sum_n state[b,n]*W[i,n] + bias[i] ----------------
__global__ void out_kernel(const uint64_t* __restrict__ fstate,
                           const float* __restrict__ W,
                           const float* __restrict__ bias,
                           float* __restrict__ out) {
    const int wg = blockIdx.x;          // b*16 + i
    const int b = wg >> 4, i = wg & 15;
    const int tid = threadIdx.x;
    const uint8_t* st = (const uint8_t*)fstate;
    const int byteoff = b >> 3, bsh = b & 7;

    float s = 0.f;
    for (int n = tid; n < N_NODES; n += 256) {
        uint32_t bit = (st[(size_t)n * 8 + byteoff] >> bsh) & 1u;
        s += (float)bit * W[(size_t)i * N_NODES + n];
    }
    #pragma unroll
    for (int off = 32; off; off >>= 1) s += __shfl_down(s, off);

    __shared__ float part[4];
    const int lane = tid & 63, wave = tid >> 6;
    if (lane == 0) part[wave] = s;
    __syncthreads();
    if (tid == 0) out[wg] = part[0] + part[1] + part[2] + part[3] + bias[i];
}

extern "C" void kernel_launch(void* const* d_in, const int* in_sizes, int n_in,
                              void* d_out, int out_size, void* d_ws, size_t ws_size,
                              hipStream_t stream) {
    const int*   x       = (const int*)d_in[0];
    const int*   adj     = (const int*)d_in[1];
    const int*   adjmask = (const int*)d_in[2];
    const int*   lut     = (const int*)d_in[3];
    const int*   initst  = (const int*)d_in[4];
    const int*   innodes = (const int*)d_in[5];
    const float* W       = (const float*)d_in[6];
    const float* bias    = (const float*)d_in[7];
    float* out = (float*)d_out;

    char* ws = (char*)d_ws;
    uint64_t* bufs  = (uint64_t*)(ws + OFF_BUFS);
    uint64_t* xmask = (uint64_t*)(ws + OFF_XMASK);
    uint32_t* ctr   = (uint32_t*)(ws + OFF_CTR);
    uint64_t* plut  = (uint64_t*)(ws + OFF_PLUT);

    {
        int prep_threads = N_NODES + NBUF + T_STEPS * INPUT_BITS + T_STEPS;
        int prep_blocks = (prep_threads + 255) / 256;
        hipLaunchKernelGGL(prep_kernel, dim3(prep_blocks), dim3(256), 0, stream,
                           x, initst, innodes, bufs, xmask, ctr);
    }

    hipLaunchKernelGGL(lutpack_kernel, dim3(N_NODES), dim3(1024), 0, stream, lut, plut);

    {
        int npw = NPW1, nwg = NWG1;
        void* args[] = { (void*)&plut, (void*)&adj, (void*)&adjmask, (void*)&innodes,
                         (void*)&xmask, (void*)&bufs, (void*)&ctr,
                         (void*)&npw, (void*)&nwg };
        hipError_t e = hipLaunchCooperativeKernel((void*)reservoir_coop,
                                                  dim3(NWG1), dim3(NTHR1),
                                                  args, 0, stream);
        if (e != hipSuccess) {
            // fallback: round-4-proven 224-WG shape
            npw = NPW2; nwg = NWG2;
            hipLaunchCooperativeKernel((void*)reservoir_coop,
                                       dim3(NWG2), dim3(NTHR2),
                                       args, 0, stream);
        }
    }

    // final states live in buf[32]
    hipLaunchKernelGGL(out_kernel, dim3(BATCH * N_INPUTS), dim3(256), 0, stream,
                       (const uint64_t*)(ws + OFF_BUFS + (size_t)T_STEPS * BUF_STRIDE_B),
                       W, bias, out);
}

// Round 8
// 364.990 us; speedup vs baseline: 1.6423x; 1.6423x over previous
//
#include <hip/hip_runtime.h>
#include <stdint.h>

#define N_NODES    50000
#define K_MAX      10
#define BATCH      64
#define T_STEPS    32
#define N_INPUTS   16
#define INPUT_BITS 64

#define NPW   224                 // nodes per workgroup
#define NWG   224                 // 14 groups x 16; NPW*NWG = 50176 >= 50000
#define NTHR  896                 // 4 threads (batch quarters) per node = 14 waves
#define GRPN  14                  // barrier tree: 14 groups
#define GRP_SZ 16                 //   of 16 WGs each
#define NBUF  (T_STEPS + 1)       // state ring: step t reads buf[t], writes buf[t+1]

#define BUF_STRIDE_B 400128u      // bytes per state buffer (50001*8 -> 128B aligned)

// ---------------- workspace layout (bytes) ----------------
#define OFF_BUFS   0u
#define OFF_XMASK  13204224u      // uint64[32*64]
#define OFF_GCTR   13220608u      // 32 steps x 14 group ctrs, each on own 256B line
#define OFF_RCTR   13335296u      // 32 root ctrs, each on own 256B line
#define OFF_PLUT   13343488u      // uint8[50176*128] packed LUT
// total ~19.77 MB

// ---------------- prep: init ring head, xor masks, sentinels, barrier ctrs ----------------
__global__ void prep_kernel(const int* __restrict__ x,
                            const int* __restrict__ init_states,
                            const int* __restrict__ input_nodes,
                            uint64_t* __restrict__ bufs,
                            uint64_t* __restrict__ xmask,
                            uint32_t* __restrict__ gctr,
                            uint32_t* __restrict__ rctr) {
    const int gid = blockIdx.x * blockDim.x + threadIdx.x;
    const size_t strw = BUF_STRIDE_B / 8;
    if (gid < N_NODES) {
        int n = gid;
        // last occurrence of n in input_nodes (last-write-wins scatter semantics)
        int jm = -1;
        for (int j = 0; j < INPUT_BITS; ++j)
            if (input_nodes[j] == n) jm = j;
        uint64_t v = init_states[n] ? ~0ull : 0ull;   // same init for all 64 batches
        if (jm >= 0) {
            uint64_t m = 0ull;
            for (int b = 0; b < BATCH; ++b)
                m |= (uint64_t)(x[b * (T_STEPS * INPUT_BITS) + jm] & 1) << b;  // t = 0
            v ^= m;
        }
        bufs[n] = v;                                  // buf[0]
    } else if (gid < N_NODES + NBUF) {
        // zero sentinel word in every ring buffer (masked-off edges point here)
        bufs[(size_t)(gid - N_NODES) * strw + N_NODES] = 0ull;
    } else if (gid < N_NODES + NBUF + T_STEPS * INPUT_BITS) {
        int k = gid - (N_NODES + NBUF);
        int t = k >> 6, j = k & 63;
        uint64_t m = 0ull;
        for (int b = 0; b < BATCH; ++b)
            m |= (uint64_t)(x[b * (T_STEPS * INPUT_BITS) + t * INPUT_BITS + j] & 1) << b;
        xmask[k] = m;
    } else {
        int c = gid - (N_NODES + NBUF + T_STEPS * INPUT_BITS);
        if (c < T_STEPS * GRPN) gctr[c * 64] = 0;                   // replay-safe
        else if (c < T_STEPS * GRPN + T_STEPS)
            rctr[(c - T_STEPS * GRPN) * 64] = 0;
    }
}

// ---------------- pack LUT to bits (full-GPU, HBM-bound): 204.8 MB -> 6.4 MB ----------------
__global__ void lutpack_kernel(const int* __restrict__ lut,
                               uint64_t* __restrict__ plut) {
    const int tid = threadIdx.x;
    const int blk = blockIdx.x;                  // node
    const int lane = tid & 63, wave = tid >> 6;  // 16 waves x 64 lanes = 1024 entries
    int v = lut[(size_t)blk * 1024 + tid];
    uint64_t m = __ballot(v & 1);
    if (lane == 0) plut[(size_t)blk * 16 + wave] = m;
}

// ---------------- cooperative kernel: all 32 steps ----------------
__global__ __launch_bounds__(NTHR)
void reservoir_coop(const uint64_t* __restrict__ plut,
                    const int* __restrict__ adj,
                    const int* __restrict__ adjmask,
                    const int* __restrict__ input_nodes,
                    const uint64_t* __restrict__ xmask,
                    uint64_t* __restrict__ bufs,
                    uint32_t* __restrict__ gctr,
                    uint32_t* __restrict__ rctr) {
    __shared__ uint8_t lutb[NPW * 128];   // 28 KB: this WG's bit-packed LUT rows

    const int tid = threadIdx.x;
    const int wg  = blockIdx.x;
    const int grp = wg >> 4;              // 0..13 (16 WGs per group)

    // ---- stage packed LUT slice -> LDS (coalesced, 32 B/thread) ----
    {
        const uint4* s = (const uint4*)(plut + (size_t)wg * NPW * 16);
        uint4* d = (uint4*)lutb;
        d[tid]        = s[tid];
        d[tid + NTHR] = s[tid + NTHR];
    }

    // ---- persistent per-thread setup (registers for all 32 steps) ----
    const int nl   = tid >> 2;            // local node (0..223)
    const int q    = tid & 3;             // batch quarter (16 batches)
    const int node = wg * NPW + nl;
    const bool valid = node < N_NODES;
    const uint32_t qsh = (uint32_t)(q & 1) * 16;

    uint32_t off[K_MAX];                  // byte offsets of gather dwords (buffer-relative)
    uint32_t soff = 0;                    // store dword byte offset (even-q lanes)
    int jm = -1;
    if (valid) {
        #pragma unroll
        for (int k = 0; k < K_MAX; ++k) {
            int a  = adj[node * K_MAX + k];
            int mk = adjmask[node * K_MAX + k];
            // masked-off neighbor -> sentinel word N_NODES (always 0)
            off[k] = (uint32_t)(mk ? a : N_NODES) * 8u + (uint32_t)(q >> 1) * 4u;
        }
        for (int j = 0; j < INPUT_BITS; ++j)
            if (input_nodes[j] == node) jm = j;   // last occurrence
        soff = (uint32_t)node * 8u + (uint32_t)(q >> 1) * 4u;
    }
    const uint32_t* lut32 = (const uint32_t*)lutb;
    const uint32_t* xm32  = (const uint32_t*)xmask;
    const int rowbase = nl * 32;          // dword index of this node's LDS LUT row
    __syncthreads();                      // LDS staging complete

    for (int t = 0; t < T_STEPS; ++t) {
        // step t: read buf[t] (plain cached loads; ring guarantees freshness),
        //         write buf[t+1] (agent-scope, visible at L3).
        const char* src = (const char*)bufs + (size_t)t * BUF_STRIDE_B;
        char*       dst = (char*)bufs + (size_t)(t + 1) * BUF_STRIDE_B;
        if (valid) {
            uint32_t w[K_MAX];
            #pragma unroll
            for (int k = 0; k < K_MAX; ++k)
                w[k] = *(const uint32_t*)(src + off[k]) >> qsh;

            uint32_t o16 = 0;
            #pragma unroll
            for (int b = 0; b < 16; ++b) {
                uint32_t idx = 0;
                #pragma unroll
                for (int k = 0; k < K_MAX; ++k)
                    idx = (idx << 1) | ((w[k] >> b) & 1u);   // k=0 -> MSB (pow2 order)
                uint32_t d = lut32[rowbase + (idx >> 5)];
                o16 |= ((d >> (idx & 31)) & 1u) << b;
            }

            // pair lanes (q even/odd) combine to one dword store
            uint32_t hi = __shfl_down(o16, 1);
            if ((q & 1) == 0) {
                uint32_t o32 = o16 | (hi << 16);
                // fold next step's input-bit XOR into this write
                if (jm >= 0 && t < T_STEPS - 1)
                    o32 ^= xm32[((t + 1) * INPUT_BITS + jm) * 2 + (q >> 1)];
                __hip_atomic_store((uint32_t*)(dst + soff), o32,
                                   __ATOMIC_RELAXED, __HIP_MEMORY_SCOPE_AGENT);
            }
        }

        if (t < T_STEPS - 1) {
            // ---- 2-level tree barrier ----
            // syncthreads drains vmcnt (sc1 stores are L3-visible before arrival).
            // 14 group lines x 16 serialized RMWs run in parallel (~0.35us),
            // then 14 root RMWs (~0.3us); everyone polls the root line (reads
            // to one line are ~1/cycle, no contention issue).
            __syncthreads();
            if (tid == 0) {
                uint32_t* gc = gctr + ((size_t)t * GRPN + grp) * 64;
                uint32_t* rc = rctr + (size_t)t * 64;
                uint32_t old = __hip_atomic_fetch_add(gc, 1u, __ATOMIC_RELAXED,
                                                      __HIP_MEMORY_SCOPE_AGENT);
                if (old == GRP_SZ - 1)
                    __hip_atomic_fetch_add(rc, 1u, __ATOMIC_RELAXED,
                                           __HIP_MEMORY_SCOPE_AGENT);
                while (__hip_atomic_load(rc, __ATOMIC_RELAXED, __HIP_MEMORY_SCOPE_AGENT)
                       < (uint32_t)GRPN)
                    __builtin_amdgcn_s_sleep(1);
            }
            __syncthreads();
        }
    }
}

// ---------------- output: out[b,i] = sum_n state[b,n]*W[i,n] + bias[i] ----------------
__global__ void out_kernel(const uint64_t* __restrict__ fstate,
                           const float* __restrict__ W,
                           const float* __restrict__ bias,
                           float* __restrict__ out) {
    const int wg = blockIdx.x;          // b*16 + i
    const int b = wg >> 4, i = wg & 15;
    const int tid = threadIdx.x;
    const uint8_t* st = (const uint8_t*)fstate;
    const int byteoff = b >> 3, bsh = b & 7;

    float s = 0.f;
    for (int n = tid; n < N_NODES; n += 256) {
        uint32_t bit = (st[(size_t)n * 8 + byteoff] >> bsh) & 1u;
        s += (float)bit * W[(size_t)i * N_NODES + n];
    }
    #pragma unroll
    for (int off = 32; off; off >>= 1) s += __shfl_down(s, off);

    __shared__ float part[4];
    const int lane = tid & 63, wave = tid >> 6;
    if (lane == 0) part[wave] = s;
    __syncthreads();
    if (tid == 0) out[wg] = part[0] + part[1] + part[2] + part[3] + bias[i];
}

extern "C" void kernel_launch(void* const* d_in, const int* in_sizes, int n_in,
                              void* d_out, int out_size, void* d_ws, size_t ws_size,
                              hipStream_t stream) {
    const int*   x       = (const int*)d_in[0];
    const int*   adj     = (const int*)d_in[1];
    const int*   adjmask = (const int*)d_in[2];
    const int*   lut     = (const int*)d_in[3];
    const int*   initst  = (const int*)d_in[4];
    const int*   innodes = (const int*)d_in[5];
    const float* W       = (const float*)d_in[6];
    const float* bias    = (const float*)d_in[7];
    float* out = (float*)d_out;

    char* ws = (char*)d_ws;
    uint64_t* bufs  = (uint64_t*)(ws + OFF_BUFS);
    uint64_t* xmask = (uint64_t*)(ws + OFF_XMASK);
    uint32_t* gctr  = (uint32_t*)(ws + OFF_GCTR);
    uint32_t* rctr  = (uint32_t*)(ws + OFF_RCTR);
    uint64_t* plut  = (uint64_t*)(ws + OFF_PLUT);

    {
        int prep_threads = N_NODES + NBUF + T_STEPS * INPUT_BITS
                         + T_STEPS * GRPN + T_STEPS;
        int prep_blocks = (prep_threads + 255) / 256;
        hipLaunchKernelGGL(prep_kernel, dim3(prep_blocks), dim3(256), 0, stream,
                           x, initst, innodes, bufs, xmask, gctr, rctr);
    }

    hipLaunchKernelGGL(lutpack_kernel, dim3(N_NODES), dim3(1024), 0, stream, lut, plut);

    {
        void* args[] = { (void*)&plut, (void*)&adj, (void*)&adjmask, (void*)&innodes,
                         (void*)&xmask, (void*)&bufs, (void*)&gctr, (void*)&rctr };
        hipLaunchCooperativeKernel((void*)reservoir_coop,
                                   dim3(NWG), dim3(NTHR),
                                   args, 0, stream);
    }

    // final states live in buf[32]
    hipLaunchKernelGGL(out_kernel, dim3(BATCH * N_INPUTS), dim3(256), 0, stream,
                       (const uint64_t*)(ws + OFF_BUFS + (size_t)T_STEPS * BUF_STRIDE_B),
                       W, bias, out);
}